// Round 3
// baseline (12470.145 us; speedup 1.0000x reference)
//
#include <hip/hip_runtime.h>

#define NPTS   2048
#define NBATCH 8
#define NPROB  24     // 8 batches x {xy, xx, yy}
#define NITER  30
#define TPB    512
#define WPB    8      // waves per block
#define BPP    42     // blocks per problem -> 1008 blocks ~ 256 CUs x 4

// eps = 0.05, log-domain Sinkhorn in log2 space.
constexpr float KSC = 28.853900817779268f;   // log2(e)/eps
constexpr float C1f = 0.38123094930796995f;  // eps*ln(2048)
constexpr float C2f = 0.03465735902799726f;  // eps*ln(2)

__device__ __forceinline__ float fexp2(float x) { return __builtin_amdgcn_exp2f(x); }
__device__ __forceinline__ float flog2(float x) { return __builtin_amdgcn_logf(x); }
__device__ __forceinline__ float fsqrt(float x) { return __builtin_amdgcn_sqrtf(x); }

// One half-pass as one kernel launch: the stream dependency IS the barrier.
// o[u] = C1 - C2*(log2 sum_j 2^(K*phi_j - K*||U_u - V_j||))
__global__ __launch_bounds__(TPB, 8)   // 8 waves/EU -> 4 blocks/CU (VGPR<=64)
void half_pass_kernel(const float* __restrict__ xyz1,
                      const float* __restrict__ xyz2,
                      float* __restrict__ fg,
                      int half)        // 0: f-update, 1: g-update
{
    __shared__ float4 sh[NPTS];        // 32 KiB: cols' coords + scaled potential

    const int tid  = threadIdx.x;
    const int lane = tid & 63;
    const int warp = tid >> 6;
    const int p    = blockIdx.x % NPROB;   // blocks of a problem share an XCD (24%8==0)
    const int lb   = blockIdx.x / NPROB;
    const int b    = p / 3;
    const int k    = p - 3 * b;            // 0: xy, 1: xx, 2: yy

    const float* xb = xyz1 + (size_t)b * NPTS * 3;
    const float* yb = xyz2 + (size_t)b * NPTS * 3;
    float* fv = fg + (size_t)p * NPTS;
    float* gv = fg + (size_t)(NPROB + p) * NPTS;

    const float* U;
    const float* V;
    const float* phi;
    float* o;
    if (half == 0) {                       // f_i update: sum over cols (y side), uses g
        U = (k == 2) ? yb : xb;
        V = (k == 1) ? xb : yb;
        phi = gv;  o = fv;
    } else {                               // g_j update: sum over rows (x side), uses new f
        U = (k == 0) ? yb : ((k == 1) ? xb : yb);
        V = (k == 2) ? yb : xb;
        phi = fv;  o = gv;
    }

    for (int j = tid; j < NPTS; j += TPB) {
        float4 t;
        t.x = V[3 * j + 0];
        t.y = V[3 * j + 1];
        t.z = V[3 * j + 2];
        t.w = KSC * phi[j];
        sh[j] = t;
    }
    __syncthreads();

    const int gw0   = lb * WPB + warp;
    const int gstep = BPP * WPB;

    for (int r = gw0; r < NPTS; r += gstep) {
        const float ux = U[3 * r + 0];
        const float uy = U[3 * r + 1];
        const float uz = U[3 * r + 2];
        float m = -3.0e38f, s = 0.0f;
        #pragma unroll
        for (int c = 0; c < 2; ++c) {
            float a[16];
            #pragma unroll
            for (int t = 0; t < 16; ++t) {
                float4 v = sh[(c * 16 + t) * 64 + lane];
                float dx = ux - v.x, dy = uy - v.y, dz = uz - v.z;
                float d2 = fmaf(dz, dz, fmaf(dy, dy, fmaf(dx, dx, 1e-12f)));
                a[t] = fmaf(-KSC, fsqrt(d2), v.w);
            }
            float cm = a[0];
            #pragma unroll
            for (int t = 1; t < 16; ++t) cm = fmaxf(cm, a[t]);
            const float nm = fmaxf(m, cm);
            float cs0 = 0.f, cs1 = 0.f, cs2 = 0.f, cs3 = 0.f;
            #pragma unroll
            for (int t = 0; t < 16; t += 4) {
                cs0 += fexp2(a[t + 0] - nm);
                cs1 += fexp2(a[t + 1] - nm);
                cs2 += fexp2(a[t + 2] - nm);
                cs3 += fexp2(a[t + 3] - nm);
            }
            s = fmaf(s, fexp2(m - nm), (cs0 + cs1) + (cs2 + cs3));
            m = nm;
        }
        #pragma unroll
        for (int off = 32; off > 0; off >>= 1) {
            float m2 = __shfl_xor(m, off);
            float s2 = __shfl_xor(s, off);
            float nm = fmaxf(m, m2);
            s = s * fexp2(m - nm) + s2 * fexp2(m2 - nm);
            m = nm;
        }
        if (lane == 0) o[r] = C1f - C2f * (m + flog2(s));
    }
}

__global__ __launch_bounds__(TPB, 1)
void reduce_kernel(const float* __restrict__ fg, float* __restrict__ out)
{
    __shared__ double red[WPB];
    const int tid  = threadIdx.x;
    const int lane = tid & 63;
    const int warp = tid >> 6;

    double acc = 0.0;
    for (int idx = tid; idx < 2 * NPROB * NPTS; idx += TPB) {
        int rem = (idx < NPROB * NPTS) ? idx : idx - NPROB * NPTS;
        int pp  = rem >> 11;             // / 2048
        int kk  = pp % 3;
        float w = (kk == 0) ? 1.0f : -0.5f;
        acc += (double)fg[idx] * (double)w;
    }
    #pragma unroll
    for (int off = 32; off > 0; off >>= 1) acc += __shfl_xor(acc, off);
    if (lane == 0) red[warp] = acc;
    __syncthreads();
    if (warp == 0) {
        double v2 = (lane < WPB) ? red[lane] : 0.0;
        #pragma unroll
        for (int off = 32; off > 0; off >>= 1) v2 += __shfl_xor(v2, off);
        if (lane == 0) out[0] = (float)(v2 / (double)(NBATCH * NPTS));
    }
}

extern "C" void kernel_launch(void* const* d_in, const int* in_sizes, int n_in,
                              void* d_out, int out_size, void* d_ws, size_t ws_size,
                              hipStream_t stream)
{
    const float* xyz1 = (const float*)d_in[0];
    const float* xyz2 = (const float*)d_in[1];
    float* out = (float*)d_out;
    float* fg  = (float*)d_ws;   // f[NPROB][NPTS] then g[NPROB][NPTS]

    // f0 = g0 = 0 (deterministic per call)
    hipMemsetAsync(fg, 0, (size_t)2 * NPROB * NPTS * sizeof(float), stream);

    for (int it = 0; it < NITER; ++it) {
        half_pass_kernel<<<NPROB * BPP, TPB, 0, stream>>>(xyz1, xyz2, fg, 0);
        half_pass_kernel<<<NPROB * BPP, TPB, 0, stream>>>(xyz1, xyz2, fg, 1);
    }
    reduce_kernel<<<1, TPB, 0, stream>>>(fg, out);
}

// Round 5
// 2843.235 us; speedup vs baseline: 4.3859x; 4.3859x over previous
//
#include <hip/hip_runtime.h>
#include <hip/hip_cooperative_groups.h>

namespace cg = cooperative_groups;

#define NPTS    2048
#define NBATCH  8
#define NPROB   24     // 8 batches x {xy, xx, yy}
#define NITER   30
#define TPB     512
#define WPB     8      // waves per block
#define BPP     32     // blocks per problem -> 768 blocks = exactly 3/CU
#define NCHUNK  32     // row chunks of 64 per problem
#define COLS_PW 256    // columns per wave

// eps = 0.05, log-domain Sinkhorn in log2 space.
constexpr float KSC = 28.853900817779268f;   // log2(e)/eps
constexpr float C1f = 0.38123094930796995f;  // eps*ln(2048)
constexpr float C2f = 0.03465735902799726f;  // eps*ln(2)

__device__ __forceinline__ float fexp2(float x) { return __builtin_amdgcn_exp2f(x); }
__device__ __forceinline__ float flog2(float x) { return __builtin_amdgcn_logf(x); }
__device__ __forceinline__ float fsqrt(float x) { return __builtin_amdgcn_sqrtf(x); }

__device__ __forceinline__ void problem_barrier(unsigned* arrive, unsigned* epoch,
                                                unsigned phase, int nbpp, int tid)
{
    __syncthreads();   // drain all waves' work before the release RMW
    if (tid == 0) {
        unsigned old = __hip_atomic_fetch_add(arrive, 1u, __ATOMIC_ACQ_REL,
                                              __HIP_MEMORY_SCOPE_AGENT);
        if (old == (unsigned)(nbpp - 1)) {
            __hip_atomic_store(arrive, 0u, __ATOMIC_RELAXED, __HIP_MEMORY_SCOPE_AGENT);
            __hip_atomic_store(epoch, phase, __ATOMIC_RELEASE, __HIP_MEMORY_SCOPE_AGENT);
        } else {
            while (__hip_atomic_load(epoch, __ATOMIC_RELAXED,
                                     __HIP_MEMORY_SCOPE_AGENT) < phase) {
                __builtin_amdgcn_s_sleep(2);
            }
            __threadfence();   // L1 invalidate so fresh phi/o are visible to this CU
        }
    }
    __syncthreads();
}

__global__ __launch_bounds__(TPB, 8)   // target <=64 VGPR -> 4 blocks/CU capacity
void sinkhorn_all(const float* __restrict__ xyz1,
                  const float* __restrict__ xyz2,
                  float* __restrict__ fg,
                  unsigned* __restrict__ bars,
                  float* __restrict__ out,
                  int nbpp)
{
    __shared__ float4 shC[NPTS];        // 32 KB: {x, y, z, K*phi} per column
    __shared__ float  shS[WPB][64];     // 2 KB: per-wave partial sums
    __shared__ double red[WPB];         // final reduce scratch

    cg::grid_group grid = cg::this_grid();

    const int tid  = threadIdx.x;
    const int lane = tid & 63;
    const int warp = tid >> 6;
    const int p    = blockIdx.x % NPROB;   // blocks of one problem share an XCD (24%8==0)
    const int lb   = blockIdx.x / NPROB;
    const int b    = p / 3;
    const int k    = p - 3 * b;            // 0: xy, 1: xx, 2: yy

    const float* xb = xyz1 + (size_t)b * NPTS * 3;
    const float* yb = xyz2 + (size_t)b * NPTS * 3;
    float* fv = fg + (size_t)p * NPTS;
    float* gv = fg + (size_t)(NPROB + p) * NPTS;
    unsigned* arrive = bars + (size_t)p * 64;
    unsigned* epoch  = bars + (size_t)p * 64 + 32;

    // rows of f-update / g-update
    const float* Uf = (k == 2) ? yb : xb;
    const float* Ug = (k == 0) ? yb : ((k == 1) ? xb : yb);

    // full stage: coords of column-side V + K*phi -> shC
    auto stage_full = [&](const float* __restrict__ V, const float* __restrict__ phi) {
        for (int c = tid; c < NPTS; c += TPB) {
            float4 t;
            t.x = V[3 * c + 0];
            t.y = V[3 * c + 1];
            t.z = V[3 * c + 2];
            t.w = KSC * phi[c];
            shC[c] = t;
        }
    };
    // w-only refresh (coords persist): one float4 of phi per thread
    auto stage_w = [&](const float* __restrict__ phi) {
        float4 ph = *(const float4*)(phi + 4 * tid);
        shC[4 * tid + 0].w = KSC * ph.x;
        shC[4 * tid + 1].w = KSC * ph.y;
        shC[4 * tid + 2].w = KSC * ph.z;
        shC[4 * tid + 3].w = KSC * ph.w;
    };

    // one half-pass over this block's row chunks; cols pre-staged in shC
    auto do_pass = [&](const float* __restrict__ U, float* __restrict__ o) {
        __syncthreads();                     // staging visible
        const int cbeg = warp * COLS_PW;
        for (int rb = lb; rb < NCHUNK; rb += nbpp) {
            const int row = (rb << 6) + lane;
            const float ux = U[3 * row + 0];
            const float uy = U[3 * row + 1];
            const float uz = U[3 * row + 2];
            float s0 = 0.f, s1 = 0.f, s2 = 0.f, s3 = 0.f;
            #pragma unroll 2
            for (int c = cbeg; c < cbeg + COLS_PW; c += 4) {
                {
                    const float4 v = shC[c + 0];
                    float dx = ux - v.x, dy = uy - v.y, dz = uz - v.z;
                    float d2 = fmaf(dx, dx, fmaf(dy, dy, fmaf(dz, dz, 1e-12f)));
                    s0 += fexp2(fmaf(-KSC, fsqrt(d2), v.w));
                }
                {
                    const float4 v = shC[c + 1];
                    float dx = ux - v.x, dy = uy - v.y, dz = uz - v.z;
                    float d2 = fmaf(dx, dx, fmaf(dy, dy, fmaf(dz, dz, 1e-12f)));
                    s1 += fexp2(fmaf(-KSC, fsqrt(d2), v.w));
                }
                {
                    const float4 v = shC[c + 2];
                    float dx = ux - v.x, dy = uy - v.y, dz = uz - v.z;
                    float d2 = fmaf(dx, dx, fmaf(dy, dy, fmaf(dz, dz, 1e-12f)));
                    s2 += fexp2(fmaf(-KSC, fsqrt(d2), v.w));
                }
                {
                    const float4 v = shC[c + 3];
                    float dx = ux - v.x, dy = uy - v.y, dz = uz - v.z;
                    float d2 = fmaf(dx, dx, fmaf(dy, dy, fmaf(dz, dz, 1e-12f)));
                    s3 += fexp2(fmaf(-KSC, fsqrt(d2), v.w));
                }
            }
            shS[warp][lane] = (s0 + s1) + (s2 + s3);
            __syncthreads();
            if (warp == 0) {
                float t = shS[0][lane];
                #pragma unroll
                for (int w = 1; w < WPB; ++w) t += shS[w][lane];
                o[(rb << 6) + lane] = C1f - C2f * flog2(t);   // coalesced 256B
            }
            __syncthreads();                 // shS reusable next chunk
        }
    };

    // static column coords for xx / yy problems (staged once)
    if (k != 0) {
        stage_full((k == 1) ? xb : yb, gv);   // w will be refreshed per pass
        __syncthreads();
    }

    for (int it = 0; it < NITER; ++it) {
        // f-pass: cols = y side (xy), static side otherwise; phi = g; out = f
        if (k == 0) stage_full(yb, gv); else stage_w(gv);
        do_pass(Uf, fv);
        problem_barrier(arrive, epoch, (unsigned)(2 * it + 1), nbpp, tid);
        // g-pass: cols = x side (xy), static side otherwise; phi = f; out = g
        if (k == 0) stage_full(xb, fv); else stage_w(fv);
        do_pass(Ug, gv);
        problem_barrier(arrive, epoch, (unsigned)(2 * it + 2), nbpp, tid);
    }

    grid.sync();   // full device barrier before the deterministic final reduce

    if (blockIdx.x == 0) {
        double acc = 0.0;
        for (int idx = tid; idx < 2 * NPROB * NPTS; idx += TPB) {
            int rem = (idx < NPROB * NPTS) ? idx : idx - NPROB * NPTS;
            int pp  = rem >> 11;             // / 2048
            int kk  = pp % 3;
            float w = (kk == 0) ? 1.0f : -0.5f;
            acc += (double)fg[idx] * (double)w;
        }
        #pragma unroll
        for (int off = 32; off > 0; off >>= 1) acc += __shfl_xor(acc, off);
        if (lane == 0) red[warp] = acc;
        __syncthreads();
        if (warp == 0) {
            double v2 = (lane < WPB) ? red[lane] : 0.0;
            #pragma unroll
            for (int off = 32; off > 0; off >>= 1) v2 += __shfl_xor(v2, off);
            if (lane == 0) out[0] = (float)(v2 / (double)(NBATCH * NPTS));
        }
    }
}

extern "C" void kernel_launch(void* const* d_in, const int* in_sizes, int n_in,
                              void* d_out, int out_size, void* d_ws, size_t ws_size,
                              hipStream_t stream)
{
    const float* xyz1 = (const float*)d_in[0];
    const float* xyz2 = (const float*)d_in[1];
    float* out = (float*)d_out;
    float* fg  = (float*)d_ws;                               // f[24][2048], g[24][2048]
    unsigned* bars = (unsigned*)((char*)d_ws + (size_t)2 * NPROB * NPTS * sizeof(float));

    // zero f/g (f0=g0=0) and barrier state each call (deterministic)
    hipMemsetAsync(d_ws, 0,
                   (size_t)2 * NPROB * NPTS * sizeof(float) +
                   (size_t)NPROB * 64 * sizeof(unsigned),
                   stream);

    // co-residency-safe blocks-per-problem (target BPP=32 -> 768 = 3/CU exact)
    int maxB = 0;
    hipOccupancyMaxActiveBlocksPerMultiprocessor(&maxB, sinkhorn_all, TPB, 0);
    if (maxB < 1) maxB = 1;
    int bpp = (maxB * 256) / NPROB;
    if (bpp > BPP) bpp = BPP;
    if (bpp < 1) bpp = 1;
    int nblk = NPROB * bpp;

    void* args[] = { (void*)&xyz1, (void*)&xyz2, (void*)&fg, (void*)&bars,
                     (void*)&out, (void*)&bpp };
    hipLaunchCooperativeKernel((void*)sinkhorn_all, dim3(nblk), dim3(TPB),
                               args, 0, stream);
}

// Round 8
// 2616.988 us; speedup vs baseline: 4.7651x; 1.0865x over previous
//
#include <hip/hip_runtime.h>
#include <hip/hip_cooperative_groups.h>

namespace cg = cooperative_groups;

#define NPTS    2048
#define NBATCH  8
#define NPROB   24     // 8 batches x {xy, xx, yy}
#define NITER   30
#define TPB     512
#define WPB     8      // waves per block
#define BPP     32     // blocks per problem -> 768 blocks = 3/CU (LDS-bound)
#define NCHUNK  32     // row chunks of 64 per problem
#define COLS_PW 256    // columns per wave

// eps = 0.05, log-domain Sinkhorn in log2 space.
constexpr float KSC = 28.853900817779268f;   // log2(e)/eps
constexpr float C1f = 0.38123094930796995f;  // eps*ln(2048)
constexpr float C2f = 0.03465735902799726f;  // eps*ln(2)

__device__ __forceinline__ float fexp2(float x) { return __builtin_amdgcn_exp2f(x); }
__device__ __forceinline__ float flog2(float x) { return __builtin_amdgcn_logf(x); }
__device__ __forceinline__ float fsqrt(float x) { return __builtin_amdgcn_sqrtf(x); }

__device__ __forceinline__ void problem_barrier(unsigned* arrive, unsigned* epoch,
                                                unsigned phase, int nbpp, int tid)
{
    __syncthreads();   // drain all waves' work before the release RMW
    if (tid == 0) {
        unsigned old = __hip_atomic_fetch_add(arrive, 1u, __ATOMIC_ACQ_REL,
                                              __HIP_MEMORY_SCOPE_AGENT);
        if (old == (unsigned)(nbpp - 1)) {
            __hip_atomic_store(arrive, 0u, __ATOMIC_RELAXED, __HIP_MEMORY_SCOPE_AGENT);
            __hip_atomic_store(epoch, phase, __ATOMIC_RELEASE, __HIP_MEMORY_SCOPE_AGENT);
        } else {
            while (__hip_atomic_load(epoch, __ATOMIC_RELAXED,
                                     __HIP_MEMORY_SCOPE_AGENT) < phase) {
                __builtin_amdgcn_s_sleep(2);
            }
            __threadfence();   // L1 invalidate so fresh phi/o are visible to this CU
        }
    }
    __syncthreads();
}

__global__ __launch_bounds__(TPB, 8)   // target <=64 VGPR -> 4 blocks/CU capacity
void sinkhorn_all(const float* __restrict__ xyz1,
                  const float* __restrict__ xyz2,
                  float* __restrict__ fg,
                  unsigned* __restrict__ bars,
                  float* __restrict__ out,
                  int nbpp)
{
    __shared__ float4 shC[NPTS];        // 32 KB: {x, y, z, K*phi} per column
    __shared__ float  shS[WPB][64];     // 2 KB: per-wave partial sums
    __shared__ double red[WPB];         // final reduce scratch

    cg::grid_group grid = cg::this_grid();

    const int tid  = threadIdx.x;
    const int lane = tid & 63;
    const int warp = tid >> 6;
    const int p    = blockIdx.x % NPROB;   // blocks of one problem share an XCD (24%8==0)
    const int lb   = blockIdx.x / NPROB;
    const int b    = p / 3;
    const int k    = p - 3 * b;            // 0: xy, 1: xx, 2: yy

    const float* xb = xyz1 + (size_t)b * NPTS * 3;
    const float* yb = xyz2 + (size_t)b * NPTS * 3;
    float* fv = fg + (size_t)p * NPTS;
    float* gv = fg + (size_t)(NPROB + p) * NPTS;
    unsigned* arrive = bars + (size_t)p * 64;
    unsigned* epoch  = bars + (size_t)p * 64 + 32;

    // rows of f-update / g-update
    const float* Uf = (k == 2) ? yb : xb;
    const float* Ug = (k == 0) ? yb : ((k == 1) ? xb : yb);

    // full stage (VECTORIZED, round-8's single change): thread t stages points
    // 4t..4t+3 via 3 aligned float4 coord loads + 1 float4 phi load, with a
    // register-only 3<->4 repack. Values written are bitwise identical to the
    // round-5 scalar stage: shC[c] = {V[3c], V[3c+1], V[3c+2], KSC*phi[c]}.
    auto stage_full = [&](const float* __restrict__ V, const float* __restrict__ phi) {
        const float4* V4 = (const float4*)V;           // 16B-aligned (24KB batch stride)
        const float4 a  = V4[3 * tid + 0];             // V[12t .. 12t+3]
        const float4 bb = V4[3 * tid + 1];             // V[12t+4 .. 12t+7]
        const float4 cc = V4[3 * tid + 2];             // V[12t+8 .. 12t+11]
        const float4 ph = *(const float4*)(phi + 4 * tid);
        const int c = 4 * tid;
        shC[c + 0] = make_float4(a.x,  a.y,  a.z,  KSC * ph.x);
        shC[c + 1] = make_float4(a.w,  bb.x, bb.y, KSC * ph.y);
        shC[c + 2] = make_float4(bb.z, bb.w, cc.x, KSC * ph.z);
        shC[c + 3] = make_float4(cc.y, cc.z, cc.w, KSC * ph.w);
    };
    // w-only refresh (coords persist): one float4 of phi per thread
    auto stage_w = [&](const float* __restrict__ phi) {
        float4 ph = *(const float4*)(phi + 4 * tid);
        shC[4 * tid + 0].w = KSC * ph.x;
        shC[4 * tid + 1].w = KSC * ph.y;
        shC[4 * tid + 2].w = KSC * ph.z;
        shC[4 * tid + 3].w = KSC * ph.w;
    };

    // one half-pass over this block's row chunks; cols pre-staged in shC
    auto do_pass = [&](const float* __restrict__ U, float* __restrict__ o) {
        __syncthreads();                     // staging visible
        const int cbeg = warp * COLS_PW;
        for (int rb = lb; rb < NCHUNK; rb += nbpp) {
            const int row = (rb << 6) + lane;
            const float ux = U[3 * row + 0];
            const float uy = U[3 * row + 1];
            const float uz = U[3 * row + 2];
            float s0 = 0.f, s1 = 0.f, s2 = 0.f, s3 = 0.f;
            #pragma unroll 2
            for (int c = cbeg; c < cbeg + COLS_PW; c += 4) {
                {
                    const float4 v = shC[c + 0];
                    float dx = ux - v.x, dy = uy - v.y, dz = uz - v.z;
                    float d2 = fmaf(dx, dx, fmaf(dy, dy, fmaf(dz, dz, 1e-12f)));
                    s0 += fexp2(fmaf(-KSC, fsqrt(d2), v.w));
                }
                {
                    const float4 v = shC[c + 1];
                    float dx = ux - v.x, dy = uy - v.y, dz = uz - v.z;
                    float d2 = fmaf(dx, dx, fmaf(dy, dy, fmaf(dz, dz, 1e-12f)));
                    s1 += fexp2(fmaf(-KSC, fsqrt(d2), v.w));
                }
                {
                    const float4 v = shC[c + 2];
                    float dx = ux - v.x, dy = uy - v.y, dz = uz - v.z;
                    float d2 = fmaf(dx, dx, fmaf(dy, dy, fmaf(dz, dz, 1e-12f)));
                    s2 += fexp2(fmaf(-KSC, fsqrt(d2), v.w));
                }
                {
                    const float4 v = shC[c + 3];
                    float dx = ux - v.x, dy = uy - v.y, dz = uz - v.z;
                    float d2 = fmaf(dx, dx, fmaf(dy, dy, fmaf(dz, dz, 1e-12f)));
                    s3 += fexp2(fmaf(-KSC, fsqrt(d2), v.w));
                }
            }
            shS[warp][lane] = (s0 + s1) + (s2 + s3);
            __syncthreads();
            if (warp == 0) {
                float t = shS[0][lane];
                #pragma unroll
                for (int w = 1; w < WPB; ++w) t += shS[w][lane];
                o[(rb << 6) + lane] = C1f - C2f * flog2(t);   // coalesced 256B
            }
            __syncthreads();                 // shS reusable next chunk
        }
    };

    // static column coords for xx / yy problems (staged once)
    if (k != 0) {
        stage_full((k == 1) ? xb : yb, gv);   // w will be refreshed per pass
        __syncthreads();
    }

    for (int it = 0; it < NITER; ++it) {
        // f-pass: cols = y side (xy), static otherwise; phi = g; out = f
        if (k == 0) stage_full(yb, gv); else stage_w(gv);
        do_pass(Uf, fv);
        problem_barrier(arrive, epoch, (unsigned)(2 * it + 1), nbpp, tid);
        // g-pass: cols = x side (xy), static otherwise; phi = f; out = g
        if (k == 0) stage_full(xb, fv); else stage_w(fv);
        do_pass(Ug, gv);
        problem_barrier(arrive, epoch, (unsigned)(2 * it + 2), nbpp, tid);
    }

    grid.sync();   // full device barrier before the deterministic final reduce

    if (blockIdx.x == 0) {
        double acc = 0.0;
        for (int idx = tid; idx < 2 * NPROB * NPTS; idx += TPB) {
            int rem = (idx < NPROB * NPTS) ? idx : idx - NPROB * NPTS;
            int pp  = rem >> 11;             // / 2048
            int kk  = pp % 3;
            float w = (kk == 0) ? 1.0f : -0.5f;
            acc += (double)fg[idx] * (double)w;
        }
        #pragma unroll
        for (int off = 32; off > 0; off >>= 1) acc += __shfl_xor(acc, off);
        if (lane == 0) red[warp] = acc;
        __syncthreads();
        if (warp == 0) {
            double v2 = (lane < WPB) ? red[lane] : 0.0;
            #pragma unroll
            for (int off = 32; off > 0; off >>= 1) v2 += __shfl_xor(v2, off);
            if (lane == 0) out[0] = (float)(v2 / (double)(NBATCH * NPTS));
        }
    }
}

extern "C" void kernel_launch(void* const* d_in, const int* in_sizes, int n_in,
                              void* d_out, int out_size, void* d_ws, size_t ws_size,
                              hipStream_t stream)
{
    const float* xyz1 = (const float*)d_in[0];
    const float* xyz2 = (const float*)d_in[1];
    float* out = (float*)d_out;
    float* fg  = (float*)d_ws;                               // f[24][2048], g[24][2048]
    unsigned* bars = (unsigned*)((char*)d_ws + (size_t)2 * NPROB * NPTS * sizeof(float));

    // zero f/g (f0=g0=0) and barrier state each call (deterministic)
    hipMemsetAsync(d_ws, 0,
                   (size_t)2 * NPROB * NPTS * sizeof(float) +
                   (size_t)NPROB * 64 * sizeof(unsigned),
                   stream);

    // co-residency-safe blocks-per-problem (target BPP=32 -> 768 = 3/CU)
    int maxB = 0;
    hipOccupancyMaxActiveBlocksPerMultiprocessor(&maxB, sinkhorn_all, TPB, 0);
    if (maxB < 1) maxB = 1;
    int bpp = (maxB * 256) / NPROB;
    if (bpp > BPP) bpp = BPP;
    if (bpp < 1) bpp = 1;
    int nblk = NPROB * bpp;

    void* args[] = { (void*)&xyz1, (void*)&xyz2, (void*)&fg, (void*)&bars,
                     (void*)&out, (void*)&bpp };
    hipLaunchCooperativeKernel((void*)sinkhorn_all, dim3(nblk), dim3(TPB),
                               args, 0, stream);
}